// Round 2
// baseline (910.652 us; speedup 1.0000x reference)
//
#include <hip/hip_runtime.h>
#include <stdint.h>

#define B_ 4
#define S_ 2048
#define D_ 2048
#define H_ 2560
#define O_ 2048
#define M_ (B_*S_)   // 8192 rows
#define NCH 16       // scan S-chunks
#define LCH (S_/NCH) // 128

typedef __attribute__((ext_vector_type(8))) short bf16x8;
typedef __attribute__((ext_vector_type(4))) float f32x4;

typedef const __attribute__((address_space(1))) unsigned int* gp32;
typedef __attribute__((address_space(3))) unsigned int* lp32;

__device__ __forceinline__ void async_cp16(const unsigned short* g, unsigned short* l) {
    __builtin_amdgcn_global_load_lds((gp32)g, (lp32)l, 16, 0, 0);
}

__device__ __forceinline__ unsigned short f2bf(float f) {
    unsigned int x = __float_as_uint(f);
    x += 0x7fffu + ((x >> 16) & 1u);   // round-to-nearest-even
    return (unsigned short)(x >> 16);
}
__device__ __forceinline__ float bf2f(unsigned short s) {
    return __uint_as_float(((unsigned int)s) << 16);
}
__device__ __forceinline__ float4 ld_bf4(const unsigned short* p) {
    const uint2 u = *(const uint2*)p;
    float4 r;
    r.x = bf2f((unsigned short)(u.x & 0xffffu));
    r.y = bf2f((unsigned short)(u.x >> 16));
    r.z = bf2f((unsigned short)(u.y & 0xffffu));
    r.w = bf2f((unsigned short)(u.y >> 16));
    return r;
}
__device__ __forceinline__ float fast_sigmoid(float x) { return 1.0f / (1.0f + __expf(-x)); }
__device__ __forceinline__ float gelu_tanh(float x) {
    // jax.nn.gelu approximate=True
    float t = 0.7978845608028654f * (x + 0.044715f * x * x * x);
    float e = __expf(2.0f * t);
    float th = 1.0f - 2.0f / (e + 1.0f);
    return 0.5f * x * (1.0f + th);
}

// ---------------- cast x fp32 -> bf16 ----------------
__global__ void cast_x_kernel(const float* __restrict__ in, unsigned short* __restrict__ out, int n4) {
    int gid = blockIdx.x * 256 + threadIdx.x;
    if (gid >= n4) return;
    const float4 v = ((const float4*)in)[gid];
    union { unsigned short s[4]; uint2 u; } pk;
    pk.s[0] = f2bf(v.x); pk.s[1] = f2bf(v.y); pk.s[2] = f2bf(v.z); pk.s[3] = f2bf(v.w);
    ((uint2*)out)[gid] = pk.u;
}

// ---------------- transpose+cast: in [K,N] fp32 -> out [N,K] bf16 ----------------
__global__ void transpose_cast_kernel(const float* __restrict__ in, unsigned short* __restrict__ out,
                                      int K, int N) {
    __shared__ float tile[64][65];
    const int t = threadIdx.x;
    const int k0 = blockIdx.y * 64, n0 = blockIdx.x * 64;
    const int r = t >> 4, c4 = (t & 15) * 4;
    #pragma unroll
    for (int p = 0; p < 4; ++p) {
        const float4 v = *(const float4*)(in + (size_t)(k0 + p*16 + r) * N + n0 + c4);
        tile[p*16 + r][c4+0] = v.x;
        tile[p*16 + r][c4+1] = v.y;
        tile[p*16 + r][c4+2] = v.z;
        tile[p*16 + r][c4+3] = v.w;
    }
    __syncthreads();
    #pragma unroll
    for (int p = 0; p < 4; ++p) {
        const int nn = n0 + p*16 + r;
        union { unsigned short s[4]; uint2 u; } pk;
        #pragma unroll
        for (int j = 0; j < 4; ++j) pk.s[j] = f2bf(tile[c4 + j][p*16 + r]);
        *(uint2*)(out + (size_t)nn * K + k0 + c4) = pk.u;
    }
}

// ---------------- bf16 MFMA GEMM (m97 structure), C[m][n] = sum_k A[m][k]*Bt[n][k] ----------------
// MODE 0: N=5120: n<H -> left=bf16(gelu(v+b0[n])); n>=H -> rin=bf16(v+b1[n-H])
// MODE 1: N=5120: n<H -> r=bf16(sigmoid(v+b0[n])); n>=H -> i=bf16(sigmoid(v+b1[n-H]))
// MODE 2: N=2048: out=fp32(v+b0[n])
template <int MODE>
__global__ __launch_bounds__(256, 2) void gemm_kernel(
        const unsigned short* __restrict__ A,
        const unsigned short* __restrict__ Bt,
        const int K,
        const float* __restrict__ bias0,
        const float* __restrict__ bias1,
        void* __restrict__ out0,
        void* __restrict__ out1)
{
    __shared__ __align__(16) unsigned short As[128*32];
    __shared__ __align__(16) unsigned short Bs[128*32];
    const int t = threadIdx.x;
    const int m0 = blockIdx.y * 128;
    const int n0 = blockIdx.x * 128;

    const unsigned short* gA = A  + (size_t)(m0 + (t >> 2)) * K + (t & 3) * 8;
    const unsigned short* gB = Bt + (size_t)(n0 + (t >> 2)) * K + (t & 3) * 8;
    unsigned short* lA0 = As + t * 8;
    unsigned short* lA1 = As + (t + 256) * 8;
    unsigned short* lB0 = Bs + t * 8;
    unsigned short* lB1 = Bs + (t + 256) * 8;
    const size_t gstep = (size_t)64 * K;

    const int lane = t & 63;
    const int w = t >> 6;
    const int wm = (w >> 1) * 64;
    const int wn = (w & 1) * 64;
    const int q8 = (lane >> 4) * 8;
    const int l16 = lane & 15;

    f32x4 acc[4][4];
    #pragma unroll
    for (int i = 0; i < 4; ++i)
        #pragma unroll
        for (int j = 0; j < 4; ++j)
            acc[i][j] = (f32x4){0.f, 0.f, 0.f, 0.f};

    for (int k0 = 0; k0 < K; k0 += 32) {
        async_cp16(gA, lA0);
        async_cp16(gA + gstep, lA1);
        async_cp16(gB, lB0);
        async_cp16(gB + gstep, lB1);
        gA += 32; gB += 32;
        __syncthreads();   // drains vmcnt for global_load_lds
        bf16x8 af[4], bfr[4];
        #pragma unroll
        for (int f = 0; f < 4; ++f)
            af[f]  = *(const bf16x8*)(As + (wm + f*16 + l16) * 32 + q8);
        #pragma unroll
        for (int f = 0; f < 4; ++f)
            bfr[f] = *(const bf16x8*)(Bs + (wn + f*16 + l16) * 32 + q8);
        #pragma unroll
        for (int fm = 0; fm < 4; ++fm)
            #pragma unroll
            for (int fn = 0; fn < 4; ++fn)
                acc[fm][fn] = __builtin_amdgcn_mfma_f32_16x16x32_bf16(af[fm], bfr[fn], acc[fm][fn], 0, 0, 0);
        __syncthreads();
    }

    const int rbase = (lane >> 4) * 4;   // C/D: col=lane&15, row=(lane>>4)*4+reg
    #pragma unroll
    for (int fm = 0; fm < 4; ++fm) {
        #pragma unroll
        for (int fn = 0; fn < 4; ++fn) {
            const int cc = n0 + wn + fn * 16 + l16;
            #pragma unroll
            for (int j = 0; j < 4; ++j) {
                const int rr = m0 + wm + fm * 16 + rbase + j;
                float v = acc[fm][fn][j];
                if (MODE == 0) {
                    if (cc < H_) {
                        ((unsigned short*)out0)[(size_t)rr * H_ + cc] = f2bf(gelu_tanh(v + bias0[cc]));
                    } else {
                        const int c2 = cc - H_;
                        ((unsigned short*)out1)[(size_t)rr * H_ + c2] = f2bf(v + bias1[c2]);
                    }
                } else if (MODE == 1) {
                    if (cc < H_) {
                        ((unsigned short*)out0)[(size_t)rr * H_ + cc] = f2bf(fast_sigmoid(v + bias0[cc]));
                    } else {
                        const int c2 = cc - H_;
                        ((unsigned short*)out1)[(size_t)rr * H_ + c2] = f2bf(fast_sigmoid(v + bias1[c2]));
                    }
                } else {
                    ((float*)out0)[(size_t)rr * O_ + cc] = v + bias0[cc];
                }
            }
        }
    }
}

// ---------------- causal depthwise conv (width 4), bf16 in -> bf16 out ----------------
__global__ void conv_kernel(const unsigned short* __restrict__ rin,
                            const float* __restrict__ cw,
                            const float* __restrict__ cb,
                            unsigned short* __restrict__ ub)
{
    const int gid = blockIdx.x * 256 + threadIdx.x;   // (b, s/4, h/4), b local to chunk
    const int h = (gid % (H_/4)) * 4;
    const int tmp = gid / (H_/4);
    const int s0 = (tmp % (S_/4)) * 4;
    const int b = tmp / (S_/4);
    const unsigned short* base = rin + (size_t)b * S_ * H_ + h;
    float4 rows[7];
    #pragma unroll
    for (int idx = 0; idx < 7; ++idx) {
        const int s = s0 - 3 + idx;
        if (s >= 0) rows[idx] = ld_bf4(base + (size_t)s * H_);
        else        rows[idx] = make_float4(0.f, 0.f, 0.f, 0.f);
    }
    float4 w[4];
    #pragma unroll
    for (int j = 0; j < 4; ++j) w[j] = *(const float4*)(cw + j * H_ + h);
    const float4 bias = *(const float4*)(cb + h);
    #pragma unroll
    for (int p = 0; p < 4; ++p) {
        float ox = bias.x, oy = bias.y, oz = bias.z, ow = bias.w;
        #pragma unroll
        for (int j = 0; j < 4; ++j) {
            ox += w[j].x * rows[p + j].x;
            oy += w[j].y * rows[p + j].y;
            oz += w[j].z * rows[p + j].z;
            ow += w[j].w * rows[p + j].w;
        }
        const size_t oidx = (size_t)b * S_ * H_ + (size_t)(s0 + p) * H_ + h;
        union { unsigned short s4[4]; uint2 uu; } pk;
        pk.s4[0] = f2bf(ox); pk.s4[1] = f2bf(oy); pk.s4[2] = f2bf(oz); pk.s4[3] = f2bf(ow);
        *(uint2*)(ub + oidx) = pk.uu;
    }
}

// ---------------- chunked RG-LRU scan (3 passes) ----------------
// pass 1: per (b, s-chunk c, h): A = prod a_t, hend = local scan from 0
__global__ void scan_pass1(const unsigned short* __restrict__ rg,
                           const unsigned short* __restrict__ ig,
                           const unsigned short* __restrict__ ub,
                           const float* __restrict__ lam,
                           float* __restrict__ Asum,
                           float* __restrict__ Hend)
{
    const int tid = blockIdx.x * 256 + threadIdx.x;  // (b*NCH + c)*H + h
    const int h = tid % H_;
    const int t2 = tid / H_;
    const int c = t2 % NCH;
    const int b = t2 / NCH;
    const float kh = -8.0f * log1pf(__expf(-lam[h]));
    size_t idx = ((size_t)b * S_ + (size_t)c * LCH) * H_ + h;
    float A = 1.f, hs = 0.f;
    #pragma unroll 4
    for (int s = 0; s < LCH; ++s, idx += H_) {
        const float rv = bf2f(rg[idx]);
        const float iv = bf2f(ig[idx]);
        const float uv = bf2f(ub[idx]);
        const float a = __expf(kh * rv);
        const float beta = sqrtf(fmaxf(1.f - a * a, 1e-12f));
        hs = a * hs + beta * iv * uv;
        A *= a;
    }
    Asum[tid] = A;
    Hend[tid] = hs;
}

// pass 2: per (b,h): sequentially combine chunk summaries; Hend[q] becomes carry-IN of chunk c
__global__ void scan_pass2(const float* __restrict__ Asum, float* __restrict__ Hend) {
    const int tid = blockIdx.x * 256 + threadIdx.x;   // b*H + h
    const int h = tid % H_;
    const int b = tid / H_;
    float hin = 0.f;
    #pragma unroll
    for (int c = 0; c < NCH; ++c) {
        const int q = (b * NCH + c) * H_ + h;
        const float Ac = Asum[q];
        const float he = Hend[q];
        Hend[q] = hin;
        hin = he + Ac * hin;
    }
}

// pass 3: replay with carry-in, write lr = left * h (bf16). lrb may alias rg (same idx in/out).
__global__ void scan_pass3(const unsigned short* __restrict__ rg,
                           const unsigned short* __restrict__ ig,
                           const unsigned short* __restrict__ ub,
                           const unsigned short* __restrict__ leftb,
                           const float* __restrict__ lam,
                           const float* __restrict__ Hin,
                           unsigned short* __restrict__ lrb)
{
    const int tid = blockIdx.x * 256 + threadIdx.x;
    const int h = tid % H_;
    const int t2 = tid / H_;
    const int c = t2 % NCH;
    const int b = t2 / NCH;
    const float kh = -8.0f * log1pf(__expf(-lam[h]));
    size_t idx = ((size_t)b * S_ + (size_t)c * LCH) * H_ + h;
    float hs = Hin[tid];
    #pragma unroll 4
    for (int s = 0; s < LCH; ++s, idx += H_) {
        const float rv = bf2f(rg[idx]);
        const float iv = bf2f(ig[idx]);
        const float uv = bf2f(ub[idx]);
        const float lf = bf2f(leftb[idx]);
        const float a = __expf(kh * rv);
        const float beta = sqrtf(fmaxf(1.f - a * a, 1e-12f));
        hs = a * hs + beta * iv * uv;
        lrb[idx] = f2bf(lf * hs);
    }
}

extern "C" void kernel_launch(void* const* d_in, const int* in_sizes, int n_in,
                              void* d_out, int out_size, void* d_ws, size_t ws_size,
                              hipStream_t stream)
{
    const float* x   = (const float*)d_in[0];
    const float* Wl  = (const float*)d_in[1];
    const float* bl  = (const float*)d_in[2];
    const float* Wr  = (const float*)d_in[3];
    const float* br  = (const float*)d_in[4];
    const float* cw  = (const float*)d_in[5];
    const float* cb  = (const float*)d_in[6];
    const float* Wa  = (const float*)d_in[7];
    const float* ba  = (const float*)d_in[8];
    const float* Wi  = (const float*)d_in[9];
    const float* bi  = (const float*)d_in[10];
    const float* lam = (const float*)d_in[11];
    const float* Wo  = (const float*)d_in[12];
    const float* bo  = (const float*)d_in[13];
    float* out = (float*)d_out;
    (void)in_sizes; (void)n_in; (void)out_size;

    const size_t wWlr = (size_t)2 * H_ * D_ * 2;   // 20.97 MB
    const size_t wWai = (size_t)2 * H_ * H_ * 2;   // 26.21 MB
    const size_t wWo  = (size_t)O_ * H_ * 2;       // 10.49 MB
    auto al = [](size_t b) { return (b + 255) & ~(size_t)255; };

    // choose batch-chunking so workspace fits: nchunk in {1,2,4}
    int nchunk = 4;
    for (int n = 1; n <= 4; n *= 2) {
        const size_t Mc = M_ / n;
        const size_t Bc = Mc / S_;
        const size_t need = al(wWlr) + al(wWai) + al(wWo)
                          + 4 * al(Mc * H_ * 2)
                          + 2 * al(Bc * NCH * H_ * 4);
        if (need <= ws_size) { nchunk = n; break; }
    }
    const int Mc = M_ / nchunk;
    const int Bc = Mc / S_;
    const size_t actB = (size_t)Mc * H_ * 2;

    char* p = (char*)d_ws;
    size_t off = 0;
    auto alloc = [&](size_t bytes) -> void* {
        void* q = p + off;
        off += al(bytes);
        return q;
    };
    unsigned short* WlrT  = (unsigned short*)alloc(wWlr);
    unsigned short* WaiT  = (unsigned short*)alloc(wWai);
    unsigned short* WoT   = (unsigned short*)alloc(wWo);
    unsigned short* slotX = (unsigned short*)alloc(actB);  // xb -> rgate -> lr
    unsigned short* slotL = (unsigned short*)alloc(actB);  // left
    unsigned short* slotR = (unsigned short*)alloc(actB);  // rin -> igate
    unsigned short* slotU = (unsigned short*)alloc(actB);  // u
    float* Asum = (float*)alloc((size_t)Bc * NCH * H_ * 4);
    float* Hend = (float*)alloc((size_t)Bc * NCH * H_ * 4);

    // weight transposes (once)
    transpose_cast_kernel<<<dim3(H_/64, D_/64), dim3(256), 0, stream>>>(Wl, WlrT, D_, H_);
    transpose_cast_kernel<<<dim3(H_/64, D_/64), dim3(256), 0, stream>>>(Wr, WlrT + (size_t)H_*D_, D_, H_);
    transpose_cast_kernel<<<dim3(H_/64, H_/64), dim3(256), 0, stream>>>(Wa, WaiT, H_, H_);
    transpose_cast_kernel<<<dim3(H_/64, H_/64), dim3(256), 0, stream>>>(Wi, WaiT + (size_t)H_*H_, H_, H_);
    transpose_cast_kernel<<<dim3(O_/64, H_/64), dim3(256), 0, stream>>>(Wo, WoT, H_, O_);

    for (int c = 0; c < nchunk; ++c) {
        const float* xc = x + (size_t)c * Mc * D_;
        float* outc = out + (size_t)c * Mc * O_;
        unsigned short* xb    = slotX;
        unsigned short* leftb = slotL;
        unsigned short* rinb  = slotR;
        unsigned short* ub    = slotU;
        unsigned short* rgb   = slotX;   // xb dead after GEMM1
        unsigned short* igb   = slotR;   // rinb dead after conv
        unsigned short* lrb   = slotX;   // in-place over rgate in pass 3

        cast_x_kernel<<<dim3(Mc*D_/4/256), dim3(256), 0, stream>>>(xc, xb, Mc*D_/4);
        gemm_kernel<0><<<dim3((2*H_)/128, Mc/128), dim3(256), 0, stream>>>(xb, WlrT, D_, bl, br, leftb, rinb);
        conv_kernel<<<dim3(Bc*S_*H_/16/256), dim3(256), 0, stream>>>(rinb, cw, cb, ub);
        gemm_kernel<1><<<dim3((2*H_)/128, Mc/128), dim3(256), 0, stream>>>(ub, WaiT, H_, ba, bi, rgb, igb);
        scan_pass1<<<dim3(Bc*NCH*H_/256), dim3(256), 0, stream>>>(rgb, igb, ub, lam, Asum, Hend);
        scan_pass2<<<dim3(Bc*H_/256), dim3(256), 0, stream>>>(Asum, Hend);
        scan_pass3<<<dim3(Bc*NCH*H_/256), dim3(256), 0, stream>>>(rgb, igb, ub, leftb, lam, Hend, lrb);
        gemm_kernel<2><<<dim3(O_/128, Mc/128), dim3(256), 0, stream>>>(lrb, WoT, H_, bo, nullptr, outc, nullptr);
    }
}

// Round 3
// 831.776 us; speedup vs baseline: 1.0948x; 1.0948x over previous
//
#include <hip/hip_runtime.h>
#include <stdint.h>

#define B_ 4
#define S_ 2048
#define D_ 2048
#define H_ 2560
#define O_ 2048
#define M_ (B_*S_)   // 8192 rows
#define NCH 16       // scan S-chunks
#define LCH (S_/NCH) // 128

typedef __attribute__((ext_vector_type(8))) short bf16x8;
typedef __attribute__((ext_vector_type(4))) float f32x4;

typedef const __attribute__((address_space(1))) unsigned int* gp32;
typedef __attribute__((address_space(3))) unsigned int* lp32;

__device__ __forceinline__ void async_cp16(const unsigned short* g, unsigned short* l) {
    __builtin_amdgcn_global_load_lds((gp32)g, (lp32)l, 16, 0, 0);
}

__device__ __forceinline__ unsigned short f2bf(float f) {
    unsigned int x = __float_as_uint(f);
    x += 0x7fffu + ((x >> 16) & 1u);   // round-to-nearest-even
    return (unsigned short)(x >> 16);
}
__device__ __forceinline__ float bf2f(unsigned short s) {
    return __uint_as_float(((unsigned int)s) << 16);
}
__device__ __forceinline__ float4 ld_bf4(const unsigned short* p) {
    const uint2 u = *(const uint2*)p;
    float4 r;
    r.x = bf2f((unsigned short)(u.x & 0xffffu));
    r.y = bf2f((unsigned short)(u.x >> 16));
    r.z = bf2f((unsigned short)(u.y & 0xffffu));
    r.w = bf2f((unsigned short)(u.y >> 16));
    return r;
}
__device__ __forceinline__ float fast_sigmoid(float x) { return 1.0f / (1.0f + __expf(-x)); }
__device__ __forceinline__ float gelu_tanh(float x) {
    // jax.nn.gelu approximate=True
    float t = 0.7978845608028654f * (x + 0.044715f * x * x * x);
    float e = __expf(2.0f * t);
    float th = 1.0f - 2.0f / (e + 1.0f);
    return 0.5f * x * (1.0f + th);
}

// ---------------- cast x fp32 -> bf16 ----------------
__global__ void cast_x_kernel(const float* __restrict__ in, unsigned short* __restrict__ out, int n4) {
    int gid = blockIdx.x * 256 + threadIdx.x;
    if (gid >= n4) return;
    const float4 v = ((const float4*)in)[gid];
    union { unsigned short s[4]; uint2 u; } pk;
    pk.s[0] = f2bf(v.x); pk.s[1] = f2bf(v.y); pk.s[2] = f2bf(v.z); pk.s[3] = f2bf(v.w);
    ((uint2*)out)[gid] = pk.u;
}

// ---------------- transpose+cast: in [K,N] fp32 -> out [N,K] bf16 ----------------
__global__ void transpose_cast_kernel(const float* __restrict__ in, unsigned short* __restrict__ out,
                                      int K, int N) {
    __shared__ float tile[64][65];
    const int t = threadIdx.x;
    const int k0 = blockIdx.y * 64, n0 = blockIdx.x * 64;
    const int r = t >> 4, c4 = (t & 15) * 4;
    #pragma unroll
    for (int p = 0; p < 4; ++p) {
        const float4 v = *(const float4*)(in + (size_t)(k0 + p*16 + r) * N + n0 + c4);
        tile[p*16 + r][c4+0] = v.x;
        tile[p*16 + r][c4+1] = v.y;
        tile[p*16 + r][c4+2] = v.z;
        tile[p*16 + r][c4+3] = v.w;
    }
    __syncthreads();
    #pragma unroll
    for (int p = 0; p < 4; ++p) {
        const int nn = n0 + p*16 + r;
        union { unsigned short s[4]; uint2 u; } pk;
        #pragma unroll
        for (int j = 0; j < 4; ++j) pk.s[j] = f2bf(tile[c4 + j][p*16 + r]);
        *(uint2*)(out + (size_t)nn * K + k0 + c4) = pk.u;
    }
}

// ---------------- bf16 MFMA GEMM, BK=64, XOR-swizzled LDS ----------------
// C[m][n] = sum_k A[m][k]*Bt[n][k]
// LDS layout: tile[row][64] halfwords, row stride 128B; within a row the 8
// 16B k-chunks are stored XOR-swizzled by (row&7). Swizzle applied on the
// GLOBAL source address (coalescing preserved: same 128B row, permuted
// chunks) so the global_load_lds dest stays linear (wave-uniform + lane*16).
// MODE 0: N=5120: n<H -> left=bf16(gelu(v+b0[n])); n>=H -> rin=bf16(v+b1[n-H])
// MODE 1: N=5120: n<H -> r=bf16(sigmoid(v+b0[n])); n>=H -> i=bf16(sigmoid(v+b1[n-H]))
// MODE 2: N=2048: out=fp32(v+b0[n])
template <int MODE>
__global__ __launch_bounds__(256, 2) void gemm_kernel(
        const unsigned short* __restrict__ A,
        const unsigned short* __restrict__ Bt,
        const int K,
        const float* __restrict__ bias0,
        const float* __restrict__ bias1,
        void* __restrict__ out0,
        void* __restrict__ out1)
{
    __shared__ __align__(16) unsigned short As[128*64];
    __shared__ __align__(16) unsigned short Bs[128*64];
    const int t = threadIdx.x;
    const int m0 = blockIdx.y * 128;
    const int n0 = blockIdx.x * 128;

    // staging: thread t covers rows {t>>3 + 32j}, k-chunk (t&7)^(row&7)
    const int srow = t >> 3;                         // 0..31
    const int csrc = ((t & 7) ^ (srow & 7)) * 8;     // element offset in row
    const unsigned short* gA = A  + (size_t)(m0 + srow) * K + csrc;
    const unsigned short* gB = Bt + (size_t)(n0 + srow) * K + csrc;
    unsigned short* lA = As + t * 8;                 // + j*2048 halfwords per call
    unsigned short* lB = Bs + t * 8;
    const size_t gstep = (size_t)32 * K;

    const int lane = t & 63;
    const int w = t >> 6;
    const int wm = (w >> 1) * 64;
    const int wn = (w & 1) * 64;
    const int q = lane >> 4;        // k-quad 0..3
    const int l16 = lane & 15;

    f32x4 acc[4][4];
    #pragma unroll
    for (int i = 0; i < 4; ++i)
        #pragma unroll
        for (int j = 0; j < 4; ++j)
            acc[i][j] = (f32x4){0.f, 0.f, 0.f, 0.f};

    for (int k0 = 0; k0 < K; k0 += 64) {
        #pragma unroll
        for (int j = 0; j < 4; ++j) {
            async_cp16(gA + j * gstep, lA + j * 2048);
            async_cp16(gB + j * gstep, lB + j * 2048);
        }
        gA += 64; gB += 64;
        __syncthreads();   // drains vmcnt for global_load_lds
        #pragma unroll
        for (int ks = 0; ks < 2; ++ks) {
            const int ch = ((q + ks * 4) ^ (l16 & 7)) * 8;   // swizzled chunk offset
            bf16x8 af[4], bfr[4];
            #pragma unroll
            for (int f = 0; f < 4; ++f)
                af[f]  = *(const bf16x8*)(As + (wm + f*16 + l16) * 64 + ch);
            #pragma unroll
            for (int f = 0; f < 4; ++f)
                bfr[f] = *(const bf16x8*)(Bs + (wn + f*16 + l16) * 64 + ch);
            #pragma unroll
            for (int fm = 0; fm < 4; ++fm)
                #pragma unroll
                for (int fn = 0; fn < 4; ++fn)
                    acc[fm][fn] = __builtin_amdgcn_mfma_f32_16x16x32_bf16(af[fm], bfr[fn], acc[fm][fn], 0, 0, 0);
        }
        __syncthreads();
    }

    const int rbase = q * 4;   // C/D: col=lane&15, row=(lane>>4)*4+reg
    #pragma unroll
    for (int fm = 0; fm < 4; ++fm) {
        #pragma unroll
        for (int fn = 0; fn < 4; ++fn) {
            const int cc = n0 + wn + fn * 16 + l16;
            #pragma unroll
            for (int j = 0; j < 4; ++j) {
                const int rr = m0 + wm + fm * 16 + rbase + j;
                float v = acc[fm][fn][j];
                if (MODE == 0) {
                    if (cc < H_) {
                        ((unsigned short*)out0)[(size_t)rr * H_ + cc] = f2bf(gelu_tanh(v + bias0[cc]));
                    } else {
                        const int c2 = cc - H_;
                        ((unsigned short*)out1)[(size_t)rr * H_ + c2] = f2bf(v + bias1[c2]);
                    }
                } else if (MODE == 1) {
                    if (cc < H_) {
                        ((unsigned short*)out0)[(size_t)rr * H_ + cc] = f2bf(fast_sigmoid(v + bias0[cc]));
                    } else {
                        const int c2 = cc - H_;
                        ((unsigned short*)out1)[(size_t)rr * H_ + c2] = f2bf(fast_sigmoid(v + bias1[c2]));
                    }
                } else {
                    ((float*)out0)[(size_t)rr * O_ + cc] = v + bias0[cc];
                }
            }
        }
    }
}

// ---------------- causal depthwise conv (width 4), bf16 in -> bf16 out ----------------
__global__ void conv_kernel(const unsigned short* __restrict__ rin,
                            const float* __restrict__ cw,
                            const float* __restrict__ cb,
                            unsigned short* __restrict__ ub)
{
    const int gid = blockIdx.x * 256 + threadIdx.x;   // (b, s/4, h/4)
    const int h = (gid % (H_/4)) * 4;
    const int tmp = gid / (H_/4);
    const int s0 = (tmp % (S_/4)) * 4;
    const int b = tmp / (S_/4);
    const unsigned short* base = rin + (size_t)b * S_ * H_ + h;
    float4 rows[7];
    #pragma unroll
    for (int idx = 0; idx < 7; ++idx) {
        const int s = s0 - 3 + idx;
        if (s >= 0) rows[idx] = ld_bf4(base + (size_t)s * H_);
        else        rows[idx] = make_float4(0.f, 0.f, 0.f, 0.f);
    }
    float4 w[4];
    #pragma unroll
    for (int j = 0; j < 4; ++j) w[j] = *(const float4*)(cw + j * H_ + h);
    const float4 bias = *(const float4*)(cb + h);
    #pragma unroll
    for (int p = 0; p < 4; ++p) {
        float ox = bias.x, oy = bias.y, oz = bias.z, ow = bias.w;
        #pragma unroll
        for (int j = 0; j < 4; ++j) {
            ox += w[j].x * rows[p + j].x;
            oy += w[j].y * rows[p + j].y;
            oz += w[j].z * rows[p + j].z;
            ow += w[j].w * rows[p + j].w;
        }
        const size_t oidx = (size_t)b * S_ * H_ + (size_t)(s0 + p) * H_ + h;
        union { unsigned short s4[4]; uint2 uu; } pk;
        pk.s4[0] = f2bf(ox); pk.s4[1] = f2bf(oy); pk.s4[2] = f2bf(oz); pk.s4[3] = f2bf(ow);
        *(uint2*)(ub + oidx) = pk.uu;
    }
}

// ---------------- chunked RG-LRU scan (3 passes) ----------------
__global__ void scan_pass1(const unsigned short* __restrict__ rg,
                           const unsigned short* __restrict__ ig,
                           const unsigned short* __restrict__ ub,
                           const float* __restrict__ lam,
                           float* __restrict__ Asum,
                           float* __restrict__ Hend)
{
    const int tid = blockIdx.x * 256 + threadIdx.x;  // (b*NCH + c)*H + h
    const int h = tid % H_;
    const int t2 = tid / H_;
    const int c = t2 % NCH;
    const int b = t2 / NCH;
    const float kh = -8.0f * log1pf(__expf(-lam[h]));
    size_t idx = ((size_t)b * S_ + (size_t)c * LCH) * H_ + h;
    float A = 1.f, hs = 0.f;
    #pragma unroll 4
    for (int s = 0; s < LCH; ++s, idx += H_) {
        const float rv = bf2f(rg[idx]);
        const float iv = bf2f(ig[idx]);
        const float uv = bf2f(ub[idx]);
        const float a = __expf(kh * rv);
        const float beta = sqrtf(fmaxf(1.f - a * a, 1e-12f));
        hs = a * hs + beta * iv * uv;
        A *= a;
    }
    Asum[tid] = A;
    Hend[tid] = hs;
}

__global__ void scan_pass2(const float* __restrict__ Asum, float* __restrict__ Hend) {
    const int tid = blockIdx.x * 256 + threadIdx.x;   // b*H + h
    const int h = tid % H_;
    const int b = tid / H_;
    float hin = 0.f;
    #pragma unroll
    for (int c = 0; c < NCH; ++c) {
        const int q = (b * NCH + c) * H_ + h;
        const float Ac = Asum[q];
        const float he = Hend[q];
        Hend[q] = hin;
        hin = he + Ac * hin;
    }
}

__global__ void scan_pass3(const unsigned short* __restrict__ rg,
                           const unsigned short* __restrict__ ig,
                           const unsigned short* __restrict__ ub,
                           const unsigned short* __restrict__ leftb,
                           const float* __restrict__ lam,
                           const float* __restrict__ Hin,
                           unsigned short* __restrict__ lrb)
{
    const int tid = blockIdx.x * 256 + threadIdx.x;
    const int h = tid % H_;
    const int t2 = tid / H_;
    const int c = t2 % NCH;
    const int b = t2 / NCH;
    const float kh = -8.0f * log1pf(__expf(-lam[h]));
    size_t idx = ((size_t)b * S_ + (size_t)c * LCH) * H_ + h;
    float hs = Hin[tid];
    #pragma unroll 4
    for (int s = 0; s < LCH; ++s, idx += H_) {
        const float rv = bf2f(rg[idx]);
        const float iv = bf2f(ig[idx]);
        const float uv = bf2f(ub[idx]);
        const float lf = bf2f(leftb[idx]);
        const float a = __expf(kh * rv);
        const float beta = sqrtf(fmaxf(1.f - a * a, 1e-12f));
        hs = a * hs + beta * iv * uv;
        lrb[idx] = f2bf(lf * hs);
    }
}

extern "C" void kernel_launch(void* const* d_in, const int* in_sizes, int n_in,
                              void* d_out, int out_size, void* d_ws, size_t ws_size,
                              hipStream_t stream)
{
    const float* x   = (const float*)d_in[0];
    const float* Wl  = (const float*)d_in[1];
    const float* bl  = (const float*)d_in[2];
    const float* Wr  = (const float*)d_in[3];
    const float* br  = (const float*)d_in[4];
    const float* cw  = (const float*)d_in[5];
    const float* cb  = (const float*)d_in[6];
    const float* Wa  = (const float*)d_in[7];
    const float* ba  = (const float*)d_in[8];
    const float* Wi  = (const float*)d_in[9];
    const float* bi  = (const float*)d_in[10];
    const float* lam = (const float*)d_in[11];
    const float* Wo  = (const float*)d_in[12];
    const float* bo  = (const float*)d_in[13];
    float* out = (float*)d_out;
    (void)in_sizes; (void)n_in; (void)out_size;

    const size_t wWlr = (size_t)2 * H_ * D_ * 2;   // 20.97 MB
    const size_t wWai = (size_t)2 * H_ * H_ * 2;   // 26.21 MB
    const size_t wWo  = (size_t)O_ * H_ * 2;       // 10.49 MB
    auto al = [](size_t b) { return (b + 255) & ~(size_t)255; };

    // choose batch-chunking so workspace fits: nchunk in {1,2,4}
    int nchunk = 4;
    for (int n = 1; n <= 4; n *= 2) {
        const size_t Mc = M_ / n;
        const size_t Bc = Mc / S_;
        const size_t need = al(wWlr) + al(wWai) + al(wWo)
                          + 4 * al(Mc * H_ * 2)
                          + 2 * al(Bc * NCH * H_ * 4);
        if (need <= ws_size) { nchunk = n; break; }
    }
    const int Mc = M_ / nchunk;
    const int Bc = Mc / S_;
    const size_t actB = (size_t)Mc * H_ * 2;

    char* p = (char*)d_ws;
    size_t off = 0;
    auto alloc = [&](size_t bytes) -> void* {
        void* q = p + off;
        off += al(bytes);
        return q;
    };
    unsigned short* WlrT  = (unsigned short*)alloc(wWlr);
    unsigned short* WaiT  = (unsigned short*)alloc(wWai);
    unsigned short* WoT   = (unsigned short*)alloc(wWo);
    unsigned short* slotX = (unsigned short*)alloc(actB);  // xb -> rgate -> lr
    unsigned short* slotL = (unsigned short*)alloc(actB);  // left
    unsigned short* slotR = (unsigned short*)alloc(actB);  // rin -> igate
    unsigned short* slotU = (unsigned short*)alloc(actB);  // u
    float* Asum = (float*)alloc((size_t)Bc * NCH * H_ * 4);
    float* Hend = (float*)alloc((size_t)Bc * NCH * H_ * 4);

    // weight transposes (once)
    transpose_cast_kernel<<<dim3(H_/64, D_/64), dim3(256), 0, stream>>>(Wl, WlrT, D_, H_);
    transpose_cast_kernel<<<dim3(H_/64, D_/64), dim3(256), 0, stream>>>(Wr, WlrT + (size_t)H_*D_, D_, H_);
    transpose_cast_kernel<<<dim3(H_/64, H_/64), dim3(256), 0, stream>>>(Wa, WaiT, H_, H_);
    transpose_cast_kernel<<<dim3(H_/64, H_/64), dim3(256), 0, stream>>>(Wi, WaiT + (size_t)H_*H_, H_, H_);
    transpose_cast_kernel<<<dim3(O_/64, H_/64), dim3(256), 0, stream>>>(Wo, WoT, H_, O_);

    for (int c = 0; c < nchunk; ++c) {
        const float* xc = x + (size_t)c * Mc * D_;
        float* outc = out + (size_t)c * Mc * O_;
        unsigned short* xb    = slotX;
        unsigned short* leftb = slotL;
        unsigned short* rinb  = slotR;
        unsigned short* ub    = slotU;
        unsigned short* rgb   = slotX;   // xb dead after GEMM1
        unsigned short* igb   = slotR;   // rinb dead after conv
        unsigned short* lrb   = slotX;   // in-place over rgate in pass 3

        cast_x_kernel<<<dim3(Mc*D_/4/256), dim3(256), 0, stream>>>(xc, xb, Mc*D_/4);
        gemm_kernel<0><<<dim3((2*H_)/128, Mc/128), dim3(256), 0, stream>>>(xb, WlrT, D_, bl, br, leftb, rinb);
        conv_kernel<<<dim3(Bc*S_*H_/16/256), dim3(256), 0, stream>>>(rinb, cw, cb, ub);
        gemm_kernel<1><<<dim3((2*H_)/128, Mc/128), dim3(256), 0, stream>>>(ub, WaiT, H_, ba, bi, rgb, igb);
        scan_pass1<<<dim3(Bc*NCH*H_/256), dim3(256), 0, stream>>>(rgb, igb, ub, lam, Asum, Hend);
        scan_pass2<<<dim3(Bc*H_/256), dim3(256), 0, stream>>>(Asum, Hend);
        scan_pass3<<<dim3(Bc*NCH*H_/256), dim3(256), 0, stream>>>(rgb, igb, ub, leftb, lam, Hend, lrb);
        gemm_kernel<2><<<dim3(O_/128, Mc/128), dim3(256), 0, stream>>>(lrb, WoT, H_, bo, nullptr, outc, nullptr);
    }
}

// Round 4
// 798.259 us; speedup vs baseline: 1.1408x; 1.0420x over previous
//
#include <hip/hip_runtime.h>
#include <stdint.h>

#define B_ 4
#define S_ 2048
#define D_ 2048
#define H_ 2560
#define O_ 2048
#define M_ (B_*S_)   // 8192 rows
#define NCH 16       // scan S-chunks
#define LCH (S_/NCH) // 128

typedef __attribute__((ext_vector_type(8))) short bf16x8;
typedef __attribute__((ext_vector_type(4))) float f32x4;

typedef const __attribute__((address_space(1))) unsigned int* gp32;
typedef __attribute__((address_space(3))) unsigned int* lp32;

__device__ __forceinline__ void async_cp16(const unsigned short* g, unsigned short* l) {
    __builtin_amdgcn_global_load_lds((gp32)g, (lp32)l, 16, 0, 0);
}

__device__ __forceinline__ unsigned short f2bf(float f) {
    unsigned int x = __float_as_uint(f);
    x += 0x7fffu + ((x >> 16) & 1u);   // round-to-nearest-even
    return (unsigned short)(x >> 16);
}
__device__ __forceinline__ float bf2f(unsigned short s) {
    return __uint_as_float(((unsigned int)s) << 16);
}
__device__ __forceinline__ float4 ld_bf4(const unsigned short* p) {
    const uint2 u = *(const uint2*)p;
    float4 r;
    r.x = bf2f((unsigned short)(u.x & 0xffffu));
    r.y = bf2f((unsigned short)(u.x >> 16));
    r.z = bf2f((unsigned short)(u.y & 0xffffu));
    r.w = bf2f((unsigned short)(u.y >> 16));
    return r;
}
__device__ __forceinline__ float fast_sigmoid(float x) { return 1.0f / (1.0f + __expf(-x)); }
__device__ __forceinline__ float gelu_tanh(float x) {
    // jax.nn.gelu approximate=True
    float t = 0.7978845608028654f * (x + 0.044715f * x * x * x);
    float e = __expf(2.0f * t);
    float th = 1.0f - 2.0f / (e + 1.0f);
    return 0.5f * x * (1.0f + th);
}

// ---------------- cast x fp32 -> bf16 ----------------
__global__ void cast_x_kernel(const float* __restrict__ in, unsigned short* __restrict__ out, int n4) {
    int gid = blockIdx.x * 256 + threadIdx.x;
    if (gid >= n4) return;
    const float4 v = ((const float4*)in)[gid];
    union { unsigned short s[4]; uint2 u; } pk;
    pk.s[0] = f2bf(v.x); pk.s[1] = f2bf(v.y); pk.s[2] = f2bf(v.z); pk.s[3] = f2bf(v.w);
    ((uint2*)out)[gid] = pk.u;
}

// ---------------- transpose+cast: in [K,N] fp32 -> out [N,K] bf16 ----------------
__global__ void transpose_cast_kernel(const float* __restrict__ in, unsigned short* __restrict__ out,
                                      int K, int N) {
    __shared__ float tile[64][65];
    const int t = threadIdx.x;
    const int k0 = blockIdx.y * 64, n0 = blockIdx.x * 64;
    const int r = t >> 4, c4 = (t & 15) * 4;
    #pragma unroll
    for (int p = 0; p < 4; ++p) {
        const float4 v = *(const float4*)(in + (size_t)(k0 + p*16 + r) * N + n0 + c4);
        tile[p*16 + r][c4+0] = v.x;
        tile[p*16 + r][c4+1] = v.y;
        tile[p*16 + r][c4+2] = v.z;
        tile[p*16 + r][c4+3] = v.w;
    }
    __syncthreads();
    #pragma unroll
    for (int p = 0; p < 4; ++p) {
        const int nn = n0 + p*16 + r;
        union { unsigned short s[4]; uint2 u; } pk;
        #pragma unroll
        for (int j = 0; j < 4; ++j) pk.s[j] = f2bf(tile[c4 + j][p*16 + r]);
        *(uint2*)(out + (size_t)nn * K + k0 + c4) = pk.u;
    }
}

// ---------------- bf16 MFMA GEMM, BK=64, XOR-swizzled LDS ----------------
// C[m][n] = sum_k A[m][k]*Bt[n][k]
// LDS layout: tile[row][64] halfwords, row stride 128B; within a row the 8
// 16B k-chunks are stored XOR-swizzled by (row&7). Swizzle applied on the
// GLOBAL source address (coalescing preserved: same 128B row, permuted
// chunks) so the global_load_lds dest stays linear (wave-uniform + lane*16).
// launch_bounds(256,4): request 4 waves/EU = 4 blocks/CU; caps vgpr+agpr at
// 128/wave (currently exactly 64+64 -> no spill).
// MODE 0: N=5120: n<H -> left=bf16(gelu(v+b0[n])); n>=H -> rin=bf16(v+b1[n-H])
// MODE 1: N=5120: n<H -> r=bf16(sigmoid(v+b0[n])); n>=H -> i=bf16(sigmoid(v+b1[n-H]))
// MODE 2: N=2048: out=fp32(v+b0[n])
template <int MODE>
__global__ __launch_bounds__(256, 4) void gemm_kernel(
        const unsigned short* __restrict__ A,
        const unsigned short* __restrict__ Bt,
        const int K,
        const float* __restrict__ bias0,
        const float* __restrict__ bias1,
        void* __restrict__ out0,
        void* __restrict__ out1)
{
    __shared__ __align__(16) unsigned short As[128*64];
    __shared__ __align__(16) unsigned short Bs[128*64];
    const int t = threadIdx.x;
    const int m0 = blockIdx.y * 128;
    const int n0 = blockIdx.x * 128;

    // staging: thread t covers rows {t>>3 + 32j}, k-chunk (t&7)^(row&7)
    const int srow = t >> 3;                         // 0..31
    const int csrc = ((t & 7) ^ (srow & 7)) * 8;     // element offset in row
    const unsigned short* gA = A  + (size_t)(m0 + srow) * K + csrc;
    const unsigned short* gB = Bt + (size_t)(n0 + srow) * K + csrc;
    unsigned short* lA = As + t * 8;                 // + j*2048 halfwords per call
    unsigned short* lB = Bs + t * 8;
    const size_t gstep = (size_t)32 * K;

    const int lane = t & 63;
    const int w = t >> 6;
    const int wm = (w >> 1) * 64;
    const int wn = (w & 1) * 64;
    const int q = lane >> 4;        // k-quad 0..3
    const int l16 = lane & 15;

    f32x4 acc[4][4];
    #pragma unroll
    for (int i = 0; i < 4; ++i)
        #pragma unroll
        for (int j = 0; j < 4; ++j)
            acc[i][j] = (f32x4){0.f, 0.f, 0.f, 0.f};

    for (int k0 = 0; k0 < K; k0 += 64) {
        #pragma unroll
        for (int j = 0; j < 4; ++j) {
            async_cp16(gA + j * gstep, lA + j * 2048);
            async_cp16(gB + j * gstep, lB + j * 2048);
        }
        gA += 64; gB += 64;
        __syncthreads();   // drains vmcnt for global_load_lds
        #pragma unroll
        for (int ks = 0; ks < 2; ++ks) {
            const int ch = ((q + ks * 4) ^ (l16 & 7)) * 8;   // swizzled chunk offset
            bf16x8 af[4], bfr[4];
            #pragma unroll
            for (int f = 0; f < 4; ++f)
                af[f]  = *(const bf16x8*)(As + (wm + f*16 + l16) * 64 + ch);
            #pragma unroll
            for (int f = 0; f < 4; ++f)
                bfr[f] = *(const bf16x8*)(Bs + (wn + f*16 + l16) * 64 + ch);
            #pragma unroll
            for (int fm = 0; fm < 4; ++fm)
                #pragma unroll
                for (int fn = 0; fn < 4; ++fn)
                    acc[fm][fn] = __builtin_amdgcn_mfma_f32_16x16x32_bf16(af[fm], bfr[fn], acc[fm][fn], 0, 0, 0);
        }
        __syncthreads();
    }

    const int rbase = q * 4;   // C/D: col=lane&15, row=(lane>>4)*4+reg
    #pragma unroll
    for (int fm = 0; fm < 4; ++fm) {
        #pragma unroll
        for (int fn = 0; fn < 4; ++fn) {
            const int cc = n0 + wn + fn * 16 + l16;
            #pragma unroll
            for (int j = 0; j < 4; ++j) {
                const int rr = m0 + wm + fm * 16 + rbase + j;
                float v = acc[fm][fn][j];
                if (MODE == 0) {
                    if (cc < H_) {
                        ((unsigned short*)out0)[(size_t)rr * H_ + cc] = f2bf(gelu_tanh(v + bias0[cc]));
                    } else {
                        const int c2 = cc - H_;
                        ((unsigned short*)out1)[(size_t)rr * H_ + c2] = f2bf(v + bias1[c2]);
                    }
                } else if (MODE == 1) {
                    if (cc < H_) {
                        ((unsigned short*)out0)[(size_t)rr * H_ + cc] = f2bf(fast_sigmoid(v + bias0[cc]));
                    } else {
                        const int c2 = cc - H_;
                        ((unsigned short*)out1)[(size_t)rr * H_ + c2] = f2bf(fast_sigmoid(v + bias1[c2]));
                    }
                } else {
                    ((float*)out0)[(size_t)rr * O_ + cc] = v + bias0[cc];
                }
            }
        }
    }
}

// ---------------- causal depthwise conv (width 4), bf16 in -> bf16 out ----------------
__global__ void conv_kernel(const unsigned short* __restrict__ rin,
                            const float* __restrict__ cw,
                            const float* __restrict__ cb,
                            unsigned short* __restrict__ ub)
{
    const int gid = blockIdx.x * 256 + threadIdx.x;   // (b, s/4, h/4)
    const int h = (gid % (H_/4)) * 4;
    const int tmp = gid / (H_/4);
    const int s0 = (tmp % (S_/4)) * 4;
    const int b = tmp / (S_/4);
    const unsigned short* base = rin + (size_t)b * S_ * H_ + h;
    float4 rows[7];
    #pragma unroll
    for (int idx = 0; idx < 7; ++idx) {
        const int s = s0 - 3 + idx;
        if (s >= 0) rows[idx] = ld_bf4(base + (size_t)s * H_);
        else        rows[idx] = make_float4(0.f, 0.f, 0.f, 0.f);
    }
    float4 w[4];
    #pragma unroll
    for (int j = 0; j < 4; ++j) w[j] = *(const float4*)(cw + j * H_ + h);
    const float4 bias = *(const float4*)(cb + h);
    #pragma unroll
    for (int p = 0; p < 4; ++p) {
        float ox = bias.x, oy = bias.y, oz = bias.z, ow = bias.w;
        #pragma unroll
        for (int j = 0; j < 4; ++j) {
            ox += w[j].x * rows[p + j].x;
            oy += w[j].y * rows[p + j].y;
            oz += w[j].z * rows[p + j].z;
            ow += w[j].w * rows[p + j].w;
        }
        const size_t oidx = (size_t)b * S_ * H_ + (size_t)(s0 + p) * H_ + h;
        union { unsigned short s4[4]; uint2 uu; } pk;
        pk.s4[0] = f2bf(ox); pk.s4[1] = f2bf(oy); pk.s4[2] = f2bf(oz); pk.s4[3] = f2bf(ow);
        *(uint2*)(ub + oidx) = pk.uu;
    }
}

// ---------------- chunked RG-LRU scan (3 passes) ----------------
__global__ void scan_pass1(const unsigned short* __restrict__ rg,
                           const unsigned short* __restrict__ ig,
                           const unsigned short* __restrict__ ub,
                           const float* __restrict__ lam,
                           float* __restrict__ Asum,
                           float* __restrict__ Hend)
{
    const int tid = blockIdx.x * 256 + threadIdx.x;  // (b*NCH + c)*H + h
    const int h = tid % H_;
    const int t2 = tid / H_;
    const int c = t2 % NCH;
    const int b = t2 / NCH;
    const float kh = -8.0f * log1pf(__expf(-lam[h]));
    size_t idx = ((size_t)b * S_ + (size_t)c * LCH) * H_ + h;
    float A = 1.f, hs = 0.f;
    #pragma unroll 4
    for (int s = 0; s < LCH; ++s, idx += H_) {
        const float rv = bf2f(rg[idx]);
        const float iv = bf2f(ig[idx]);
        const float uv = bf2f(ub[idx]);
        const float a = __expf(kh * rv);
        const float beta = sqrtf(fmaxf(1.f - a * a, 1e-12f));
        hs = a * hs + beta * iv * uv;
        A *= a;
    }
    Asum[tid] = A;
    Hend[tid] = hs;
}

__global__ void scan_pass2(const float* __restrict__ Asum, float* __restrict__ Hend) {
    const int tid = blockIdx.x * 256 + threadIdx.x;   // b*H + h
    const int h = tid % H_;
    const int b = tid / H_;
    float hin = 0.f;
    #pragma unroll
    for (int c = 0; c < NCH; ++c) {
        const int q = (b * NCH + c) * H_ + h;
        const float Ac = Asum[q];
        const float he = Hend[q];
        Hend[q] = hin;
        hin = he + Ac * hin;
    }
}

__global__ void scan_pass3(const unsigned short* __restrict__ rg,
                           const unsigned short* __restrict__ ig,
                           const unsigned short* __restrict__ ub,
                           const unsigned short* __restrict__ leftb,
                           const float* __restrict__ lam,
                           const float* __restrict__ Hin,
                           unsigned short* __restrict__ lrb)
{
    const int tid = blockIdx.x * 256 + threadIdx.x;
    const int h = tid % H_;
    const int t2 = tid / H_;
    const int c = t2 % NCH;
    const int b = t2 / NCH;
    const float kh = -8.0f * log1pf(__expf(-lam[h]));
    size_t idx = ((size_t)b * S_ + (size_t)c * LCH) * H_ + h;
    float hs = Hin[tid];
    #pragma unroll 4
    for (int s = 0; s < LCH; ++s, idx += H_) {
        const float rv = bf2f(rg[idx]);
        const float iv = bf2f(ig[idx]);
        const float uv = bf2f(ub[idx]);
        const float lf = bf2f(leftb[idx]);
        const float a = __expf(kh * rv);
        const float beta = sqrtf(fmaxf(1.f - a * a, 1e-12f));
        hs = a * hs + beta * iv * uv;
        lrb[idx] = f2bf(lf * hs);
    }
}

extern "C" void kernel_launch(void* const* d_in, const int* in_sizes, int n_in,
                              void* d_out, int out_size, void* d_ws, size_t ws_size,
                              hipStream_t stream)
{
    const float* x   = (const float*)d_in[0];
    const float* Wl  = (const float*)d_in[1];
    const float* bl  = (const float*)d_in[2];
    const float* Wr  = (const float*)d_in[3];
    const float* br  = (const float*)d_in[4];
    const float* cw  = (const float*)d_in[5];
    const float* cb  = (const float*)d_in[6];
    const float* Wa  = (const float*)d_in[7];
    const float* ba  = (const float*)d_in[8];
    const float* Wi  = (const float*)d_in[9];
    const float* bi  = (const float*)d_in[10];
    const float* lam = (const float*)d_in[11];
    const float* Wo  = (const float*)d_in[12];
    const float* bo  = (const float*)d_in[13];
    float* out = (float*)d_out;
    (void)in_sizes; (void)n_in; (void)out_size;

    const size_t wWlr = (size_t)2 * H_ * D_ * 2;   // 20.97 MB
    const size_t wWai = (size_t)2 * H_ * H_ * 2;   // 26.21 MB
    const size_t wWo  = (size_t)O_ * H_ * 2;       // 10.49 MB
    auto al = [](size_t b) { return (b + 255) & ~(size_t)255; };

    // choose batch-chunking so workspace fits: nchunk in {1,2,4}
    int nchunk = 4;
    for (int n = 1; n <= 4; n *= 2) {
        const size_t Mc = M_ / n;
        const size_t Bc = Mc / S_;
        const size_t need = al(wWlr) + al(wWai) + al(wWo)
                          + 4 * al(Mc * H_ * 2)
                          + 2 * al(Bc * NCH * H_ * 4);
        if (need <= ws_size) { nchunk = n; break; }
    }
    const int Mc = M_ / nchunk;
    const int Bc = Mc / S_;
    const size_t actB = (size_t)Mc * H_ * 2;

    char* p = (char*)d_ws;
    size_t off = 0;
    auto alloc = [&](size_t bytes) -> void* {
        void* q = p + off;
        off += al(bytes);
        return q;
    };
    unsigned short* WlrT  = (unsigned short*)alloc(wWlr);
    unsigned short* WaiT  = (unsigned short*)alloc(wWai);
    unsigned short* WoT   = (unsigned short*)alloc(wWo);
    unsigned short* slotX = (unsigned short*)alloc(actB);  // xb -> rgate -> lr
    unsigned short* slotL = (unsigned short*)alloc(actB);  // left
    unsigned short* slotR = (unsigned short*)alloc(actB);  // rin -> igate
    unsigned short* slotU = (unsigned short*)alloc(actB);  // u
    float* Asum = (float*)alloc((size_t)Bc * NCH * H_ * 4);
    float* Hend = (float*)alloc((size_t)Bc * NCH * H_ * 4);

    // weight transposes (once)
    transpose_cast_kernel<<<dim3(H_/64, D_/64), dim3(256), 0, stream>>>(Wl, WlrT, D_, H_);
    transpose_cast_kernel<<<dim3(H_/64, D_/64), dim3(256), 0, stream>>>(Wr, WlrT + (size_t)H_*D_, D_, H_);
    transpose_cast_kernel<<<dim3(H_/64, H_/64), dim3(256), 0, stream>>>(Wa, WaiT, H_, H_);
    transpose_cast_kernel<<<dim3(H_/64, H_/64), dim3(256), 0, stream>>>(Wi, WaiT + (size_t)H_*H_, H_, H_);
    transpose_cast_kernel<<<dim3(O_/64, H_/64), dim3(256), 0, stream>>>(Wo, WoT, H_, O_);

    for (int c = 0; c < nchunk; ++c) {
        const float* xc = x + (size_t)c * Mc * D_;
        float* outc = out + (size_t)c * Mc * O_;
        unsigned short* xb    = slotX;
        unsigned short* leftb = slotL;
        unsigned short* rinb  = slotR;
        unsigned short* ub    = slotU;
        unsigned short* rgb   = slotX;   // xb dead after GEMM1
        unsigned short* igb   = slotR;   // rinb dead after conv
        unsigned short* lrb   = slotX;   // in-place over rgate in pass 3

        cast_x_kernel<<<dim3(Mc*D_/4/256), dim3(256), 0, stream>>>(xc, xb, Mc*D_/4);
        gemm_kernel<0><<<dim3((2*H_)/128, Mc/128), dim3(256), 0, stream>>>(xb, WlrT, D_, bl, br, leftb, rinb);
        conv_kernel<<<dim3(Bc*S_*H_/16/256), dim3(256), 0, stream>>>(rinb, cw, cb, ub);
        gemm_kernel<1><<<dim3((2*H_)/128, Mc/128), dim3(256), 0, stream>>>(ub, WaiT, H_, ba, bi, rgb, igb);
        scan_pass1<<<dim3(Bc*NCH*H_/256), dim3(256), 0, stream>>>(rgb, igb, ub, lam, Asum, Hend);
        scan_pass2<<<dim3(Bc*H_/256), dim3(256), 0, stream>>>(Asum, Hend);
        scan_pass3<<<dim3(Bc*NCH*H_/256), dim3(256), 0, stream>>>(rgb, igb, ub, leftb, lam, Hend, lrb);
        gemm_kernel<2><<<dim3(O_/128, Mc/128), dim3(256), 0, stream>>>(lrb, WoT, H_, bo, nullptr, outc, nullptr);
    }
}